// Round 12
// baseline (100.293 us; speedup 1.0000x reference)
//
#include <hip/hip_runtime.h>
#include <stdint.h>

#define NTREES 8
#define NNODES 5
#define CC 16
#define BB 8
#define HH 224
#define WW 224
#define NBAND 56          // 224 / 4 rows per band

struct Forest { int par[NTREES * NNODES]; };
struct Cls { int v[NTREES]; };

// ---------------------------------------------------------------------------
// Host-side bit-exact reproduction of np.random.default_rng(0) forest
// (verified absmax 0.0 vs numpy in rounds 1-11 — do not touch).
// ---------------------------------------------------------------------------
namespace nprng {

struct Pcg {
  __uint128_t state, inc;
  int has_uint32;
  uint32_t uinteger;
};

static inline __uint128_t pcg_mult() {
  return (((__uint128_t)0x2360ED051FC65DA4ULL) << 64) | 0x4385DF649FCCF645ULL;
}

static inline void pcg_step(Pcg& s) { s.state = s.state * pcg_mult() + s.inc; }

static inline uint64_t pcg_next64(Pcg& s) {
  pcg_step(s);
  uint64_t xored = (uint64_t)(s.state >> 64) ^ (uint64_t)s.state;
  unsigned rot = (unsigned)(s.state >> 122);
  return (xored >> rot) | (xored << ((64u - rot) & 63u));
}

static inline uint32_t pcg_next32(Pcg& s) {
  if (s.has_uint32) { s.has_uint32 = 0; return s.uinteger; }
  uint64_t n = pcg_next64(s);
  s.has_uint32 = 1;
  s.uinteger = (uint32_t)(n >> 32);
  return (uint32_t)n;
}

static inline uint32_t lemire32(Pcg& s, uint32_t rng) {
  const uint32_t rng_excl = rng + 1u;
  uint64_t m = (uint64_t)pcg_next32(s) * (uint64_t)rng_excl;
  uint32_t leftover = (uint32_t)m;
  if (leftover < rng_excl) {
    const uint32_t threshold = (uint32_t)((0xFFFFFFFFu - rng) % rng_excl);
    while (leftover < threshold) {
      m = (uint64_t)pcg_next32(s) * (uint64_t)rng_excl;
      leftover = (uint32_t)m;
    }
  }
  return (uint32_t)(m >> 32);
}

static void make_forest(Forest& f) {
  const uint32_t INIT_A = 0x43b0d7e5u, MULT_A = 0x931e8875u;
  const uint32_t INIT_B = 0x8b51f9ddu, MULT_B = 0x58f38dedu;
  const uint32_t MIX_L  = 0xca01f9ddu, MIX_R  = 0x4973f715u;
  uint32_t pool[4];
  uint32_t hc = INIT_A;
  auto hashmix = [&](uint32_t v) -> uint32_t {
    v ^= hc; hc *= MULT_A; v *= hc; v ^= v >> 16; return v;
  };
  auto mix = [&](uint32_t x, uint32_t y) -> uint32_t {
    uint32_t r = MIX_L * x - MIX_R * y; r ^= r >> 16; return r;
  };
  pool[0] = hashmix(0u);
  for (int i = 1; i < 4; ++i) pool[i] = hashmix(0u);
  for (int is = 0; is < 4; ++is)
    for (int id = 0; id < 4; ++id)
      if (is != id) pool[id] = mix(pool[id], hashmix(pool[is]));
  uint32_t st32[8];
  uint32_t hb = INIT_B;
  for (int i = 0; i < 8; ++i) {
    uint32_t dv = pool[i & 3];
    dv ^= hb; hb *= MULT_B; dv *= hb; dv ^= dv >> 16;
    st32[i] = dv;
  }
  uint64_t w64[4];
  for (int i = 0; i < 4; ++i)
    w64[i] = (uint64_t)st32[2 * i] | ((uint64_t)st32[2 * i + 1] << 32);

  __uint128_t initstate = (((__uint128_t)w64[0]) << 64) | w64[1];
  __uint128_t initseq   = (((__uint128_t)w64[2]) << 64) | w64[3];
  Pcg s;
  s.state = 0; s.inc = (initseq << 1) | 1;
  pcg_step(s);
  s.state += initstate;
  pcg_step(s);
  s.has_uint32 = 0; s.uinteger = 0;

  for (int t = 0; t < NTREES; ++t) {
    f.par[t * NNODES + 0] = -1;
    for (int i = 1; i < NNODES; ++i) {
      uint32_t rng = (uint32_t)(i - 1);
      f.par[t * NNODES + i] = (rng == 0) ? 0 : (int)lemire32(s, rng);
    }
  }
}

}  // namespace nprng

// ---------------------------------------------------------------------------
// Tree-shape classification + level-form class configs (verified absmax 0.0
// in R8/R10/R11): chain C1 = fv*sL^E1L; C2 = fv*sL^E2L*sC1; C3 = fv*sC2;
// root = fv*sL^RL*sC1^R1*sC2^R2*sC3^R3.
// ---------------------------------------------------------------------------
static int classify_tree(const int* p) {
  int nch[NNODES] = {0, 0, 0, 0, 0};
  for (int i = 1; i < NNODES; ++i) nch[p[i]]++;
  int internals[3], nI = 0;
  for (int i = 1; i <= 3; ++i) if (nch[i] > 0) internals[nI++] = i;
  if (nI == 0) return 1;
  if (nI == 1) {
    int m = nch[internals[0]];
    return m == 1 ? 2 : (m == 2 ? 3 : 4);
  }
  if (nI == 2) {
    int i = internals[0], j = internals[1];
    if (p[j] == i) {
      if (nch[j] == 2) return 9;
      return (nch[i] - 1 == 1) ? 7 : 6;
    }
    return 5;
  }
  return 8;
}

template <int CL> struct TC;
template <> struct TC<1> { static constexpr int H1=0,E1L=0,H2=0,E2L=0,H3=0,RL=4,R1=0,R2=0,R3=0; };
template <> struct TC<2> { static constexpr int H1=1,E1L=1,H2=0,E2L=0,H3=0,RL=2,R1=1,R2=0,R3=0; };
template <> struct TC<3> { static constexpr int H1=1,E1L=2,H2=0,E2L=0,H3=0,RL=1,R1=1,R2=0,R3=0; };
template <> struct TC<4> { static constexpr int H1=1,E1L=3,H2=0,E2L=0,H3=0,RL=0,R1=1,R2=0,R3=0; };
template <> struct TC<5> { static constexpr int H1=1,E1L=1,H2=0,E2L=0,H3=0,RL=0,R1=2,R2=0,R3=0; };
template <> struct TC<6> { static constexpr int H1=1,E1L=1,H2=1,E2L=0,H3=0,RL=1,R1=0,R2=1,R3=0; };
template <> struct TC<7> { static constexpr int H1=1,E1L=1,H2=1,E2L=1,H3=0,RL=0,R1=0,R2=1,R3=0; };
template <> struct TC<8> { static constexpr int H1=1,E1L=1,H2=1,E2L=0,H3=1,RL=0,R1=0,R2=0,R3=1; };
template <> struct TC<9> { static constexpr int H1=1,E1L=2,H2=1,E2L=0,H3=0,RL=0,R1=0,R2=1,R3=0; };

// ---------------------------------------------------------------------------
// DPP helpers (product space, max identity 0.0; patterns verified R4-R11).
// SCAN4: 4 independent inclusive 64-lane max-scans, stage-major interleaved
// (dependent same-register DPPs 3 insts apart >= 2 required wait states).
// ---------------------------------------------------------------------------
__device__ __forceinline__ float wshr1(float t) {
  int r = __builtin_amdgcn_update_dpp(
      0, __builtin_bit_cast(int, t), 0x138, 0xf, 0xf, true);  // wave_shr:1
  return __builtin_bit_cast(float, r);
}

#define S4STAGE(MODS) \
  "v_max_f32_dpp %0, %0, %0 " MODS "\n\t" \
  "v_max_f32_dpp %1, %1, %1 " MODS "\n\t" \
  "v_max_f32_dpp %2, %2, %2 " MODS "\n\t" \
  "v_max_f32_dpp %3, %3, %3 " MODS "\n\t"

#define SCAN4(a, b, c, d)                                     \
  asm volatile(                                               \
      "s_nop 1\n\t"                                           \
      S4STAGE("row_shr:1 row_mask:0xf bank_mask:0xf")         \
      S4STAGE("row_shr:2 row_mask:0xf bank_mask:0xf")         \
      S4STAGE("row_shr:4 row_mask:0xf bank_mask:0xf")         \
      S4STAGE("row_shr:8 row_mask:0xf bank_mask:0xf")         \
      S4STAGE("row_bcast:15 row_mask:0xa bank_mask:0xf")      \
      S4STAGE("row_bcast:31 row_mask:0xc bank_mask:0xf")      \
      "s_nop 1"                                               \
      : "+v"(a), "+v"(b), "+v"(c), "+v"(d))

#define MUL4(d, s) { (d).x *= (s).x; (d).y *= (s).y; (d).z *= (s).z; (d).w *= (s).w; }
#define MAX4(d, s) { (d).x = fmaxf((d).x,(s).x); (d).y = fmaxf((d).y,(s).y); \
                     (d).z = fmaxf((d).z,(s).z); (d).w = fmaxf((d).w,(s).w); }

template <int E>
__device__ __forceinline__ void powmul(float4& v, const float4& s) {
  if constexpr (E == 4) {
    float4 t = s; MUL4(t, t); MUL4(t, t); MUL4(v, t);
  } else {
    if constexpr (E >= 1) MUL4(v, s);
    if constexpr (E >= 2) MUL4(v, s);
    if constexpr (E >= 3) MUL4(v, s);
  }
}

// One level pass over a 4-row band, SHIFTED-SPACE state:
// S(h) = shift(M(h)); S(h) = max(S(h-1), shift(P(h))) with
// shift(P) = (e, max(e,l0), max(e,l1), max(e,l2)), e = wshr1(q).
// carry = S at (band start - 1), read-only here (caller updates at band end).
__device__ __forceinline__ void scan_pass(const float4 v[4], float4 S[4],
                                          const float4& carry) {
  float l1a = fmaxf(v[0].x, v[0].y), l2a = fmaxf(l1a, v[0].z), qa = fmaxf(l2a, v[0].w);
  float l1b = fmaxf(v[1].x, v[1].y), l2b = fmaxf(l1b, v[1].z), qb = fmaxf(l2b, v[1].w);
  float l1c = fmaxf(v[2].x, v[2].y), l2c = fmaxf(l1c, v[2].z), qc = fmaxf(l2c, v[2].w);
  float l1d = fmaxf(v[3].x, v[3].y), l2d = fmaxf(l1d, v[3].z), qd = fmaxf(l2d, v[3].w);
  SCAN4(qa, qb, qc, qd);
  float4 run = carry;
  {
    float e = wshr1(qa);
    run.x = fmaxf(run.x, e);
    run.y = fmaxf(run.y, fmaxf(e, v[0].x));
    run.z = fmaxf(run.z, fmaxf(e, l1a));
    run.w = fmaxf(run.w, fmaxf(e, l2a));
    S[0] = run;
  }
  {
    float e = wshr1(qb);
    run.x = fmaxf(run.x, e);
    run.y = fmaxf(run.y, fmaxf(e, v[1].x));
    run.z = fmaxf(run.z, fmaxf(e, l1b));
    run.w = fmaxf(run.w, fmaxf(e, l2b));
    S[1] = run;
  }
  {
    float e = wshr1(qc);
    run.x = fmaxf(run.x, e);
    run.y = fmaxf(run.y, fmaxf(e, v[2].x));
    run.z = fmaxf(run.z, fmaxf(e, l1c));
    run.w = fmaxf(run.w, fmaxf(e, l2c));
    S[2] = run;
  }
  {
    float e = wshr1(qd);
    run.x = fmaxf(run.x, e);
    run.y = fmaxf(run.y, fmaxf(e, v[3].x));
    run.z = fmaxf(run.z, fmaxf(e, l1d));
    run.w = fmaxf(run.w, fmaxf(e, l2d));
    S[3] = run;
  }
}

// ---------------------------------------------------------------------------
// Band-4 level-pass DP, one wave per (tree,b,c). Product space (exp
// isomorphism, verified R6-R11): f=(1+relu(x))*mask, sentinel 0.0,
// out = exp(asum)*m - 1. Consumers read the previous level's shifted state
// DIRECTLY (no DPP): src at row u = (u==0) ? band-carry : S[u-1].
// Register-lean vs R11: worst class ~160 VGPR (was ~290, over the 256 limit
// -> spill suspicion). Blocks 128 apart share an x-plane -> same XCD.
// ---------------------------------------------------------------------------
template <int CL>
__device__ __forceinline__ void run_tree(const float* __restrict__ cp,
                                         float mask, float asum,
                                         float* __restrict__ outp, int lane) {
  using F = TC<CL>;
  const float4 z4 = make_float4(0.f, 0.f, 0.f, 0.f);
  float4 cL = z4, c1 = z4, c2 = z4, c3 = z4, racc = z4;

  float4 X[4];
#pragma unroll
  for (int u = 0; u < 4; ++u) X[u] = *(const float4*)(cp + u * WW);

#pragma unroll 1
  for (int band = 0; band < NBAND; ++band) {
    const int nb = (band + 1 < NBAND) ? band + 1 : NBAND - 1;
    float4 T[4];
#pragma unroll
    for (int u = 0; u < 4; ++u)
      T[u] = *(const float4*)(cp + (size_t)(nb * 4 + u) * WW);

    float4 fv[4];
#pragma unroll
    for (int u = 0; u < 4; ++u) {
      const float4 xr = X[u];
      fv[u].x = fmaf(fmaxf(xr.x, 0.f), mask, mask);
      fv[u].y = fmaf(fmaxf(xr.y, 0.f), mask, mask);
      fv[u].z = fmaf(fmaxf(xr.z, 0.f), mask, mask);
      fv[u].w = fmaf(fmaxf(xr.w, 0.f), mask, mask);
    }

    float4 SL[4], S1[4], S2[4], S3[4];

    // pass 0: leaf chain (v = fv)
    scan_pass(fv, SL, cL);

    // pass 1: C1 = fv * sL^E1L
    if constexpr (F::H1) {
      float4 v[4];
#pragma unroll
      for (int u = 0; u < 4; ++u) {
        v[u] = fv[u];
        powmul<F::E1L>(v[u], (u == 0) ? cL : SL[u - 1]);
      }
      scan_pass(v, S1, c1);
    }

    // pass 2: C2 = fv * sL^E2L * sC1
    if constexpr (F::H2) {
      float4 v[4];
#pragma unroll
      for (int u = 0; u < 4; ++u) {
        v[u] = fv[u];
        if constexpr (F::E2L > 0) powmul<F::E2L>(v[u], (u == 0) ? cL : SL[u - 1]);
        { float4 s = (u == 0) ? c1 : S1[u - 1]; MUL4(v[u], s); }
      }
      scan_pass(v, S2, c2);
    }

    // pass 3: C3 = fv * sC2
    if constexpr (F::H3) {
      float4 v[4];
#pragma unroll
      for (int u = 0; u < 4; ++u) {
        v[u] = fv[u];
        { float4 s = (u == 0) ? c2 : S2[u - 1]; MUL4(v[u], s); }
      }
      scan_pass(v, S3, c3);
    }

    // root pass: r = fv * sL^RL * sC1^R1 * sC2^R2 * sC3^R3 (all at row h-1)
#pragma unroll
    for (int u = 0; u < 4; ++u) {
      float4 r = fv[u];
      if constexpr (F::RL > 0) powmul<F::RL>(r, (u == 0) ? cL : SL[u - 1]);
      if constexpr (F::R1 > 0) powmul<F::R1>(r, (u == 0) ? c1 : S1[u - 1]);
      if constexpr (F::R2 > 0) powmul<F::R2>(r, (u == 0) ? c2 : S2[u - 1]);
      if constexpr (F::R3 > 0) powmul<F::R3>(r, (u == 0) ? c3 : S3[u - 1]);
      MAX4(racc, r);
    }

    // band carries (after ALL uses of the old values)
    cL = SL[3];
    if constexpr (F::H1) c1 = S1[3];
    if constexpr (F::H2) c2 = S2[3];
    if constexpr (F::H3) c3 = S3[3];

#pragma unroll
    for (int u = 0; u < 4; ++u) X[u] = T[u];
  }

  float m = fmaxf(fmaxf(racc.x, racc.y), fmaxf(racc.z, racc.w));
#pragma unroll
  for (int d = 1; d < 64; d <<= 1) m = fmaxf(m, __shfl_xor(m, d));
  if (lane == 0) *outp = expf(asum) * m - 1.f;
}

__global__ __launch_bounds__(64) void fis_kernel(const float* __restrict__ x,
                                                 const float* __restrict__ alphas,
                                                 float* __restrict__ out,
                                                 Cls cls) {
  const int lane = threadIdx.x;
  const int blk  = blockIdx.x;
  const int t    = blk >> 7;     // blocks 128 apart share x-plane -> same XCD
  const int bc   = blk & 127;
  const int c    = bc & (CC - 1);
  const int b    = bc >> 4;

  const float* __restrict__ xp = x + (size_t)bc * (HH * WW);

  float asum = 0.f;
#pragma unroll
  for (int i = 0; i < NNODES; ++i) asum += alphas[(t * NNODES + i) * CC + c];

  const int   w0   = lane * 4;
  const float mask = (w0 < WW) ? 1.0f : 0.0f;
  const float* __restrict__ cp = xp + ((w0 < WW) ? w0 : (WW - 4));
  float* outp = out + ((size_t)b * NTREES + t) * CC + c;

  switch (cls.v[t]) {
    case 1: run_tree<1>(cp, mask, asum, outp, lane); break;
    case 2: run_tree<2>(cp, mask, asum, outp, lane); break;
    case 3: run_tree<3>(cp, mask, asum, outp, lane); break;
    case 4: run_tree<4>(cp, mask, asum, outp, lane); break;
    case 5: run_tree<5>(cp, mask, asum, outp, lane); break;
    case 6: run_tree<6>(cp, mask, asum, outp, lane); break;
    case 7: run_tree<7>(cp, mask, asum, outp, lane); break;
    case 8: run_tree<8>(cp, mask, asum, outp, lane); break;
    case 9: run_tree<9>(cp, mask, asum, outp, lane); break;
    default: break;
  }
}

extern "C" void kernel_launch(void* const* d_in, const int* in_sizes, int n_in,
                              void* d_out, int out_size, void* d_ws, size_t ws_size,
                              hipStream_t stream) {
  const float* x      = (const float*)d_in[0];
  const float* alphas = (const float*)d_in[1];
  float* out          = (float*)d_out;

  Forest f;
  nprng::make_forest(f);  // deterministic; same every call (graph-capture safe)

  Cls cls;
  for (int t = 0; t < NTREES; ++t)
    cls.v[t] = classify_tree(&f.par[t * NNODES]);

  dim3 grid(BB * CC * NTREES);  // 1024 single-wave blocks
  dim3 block(64);
  hipLaunchKernelGGL(fis_kernel, grid, block, 0, stream, x, alphas, out, cls);
}